// Round 17
// baseline (323.024 us; speedup 1.0000x reference)
//
#include <hip/hip_runtime.h>

// ---------------------------------------------------------------------------
// StateBank R17 = R15/R16 with: (1) gemm_big at 3 blocks/CU (48KB dbuf,
// launch_bounds(256,3)) — clean occupancy A/B at fixed tile; (2) scanB with
// 4 d/thread uint2 Y-loads (8B/lane); (3) u-pass split to 256 blocks.
// gemm_big K-loop/epilogue otherwise byte-identical to R15 (best: 153.2us,
// gemm 84.5us @ 35% MfmaUtil, conflict-free, counted vmcnt(6)).
// ---------------------------------------------------------------------------

#define Bb 4
#define Tt 2048
#define Dd 1024
#define Kk 4
#define BT (Bb*Tt)          // 8192
#define Ee (Kk*Dd)          // 4096
#define NCH 32              // scan chunks
#define LCH 64              // chunk length (NCH*LCH = T)

typedef __bf16 bf16x8 __attribute__((ext_vector_type(8)));
typedef float  f32x4  __attribute__((ext_vector_type(4)));
typedef float  f32x2  __attribute__((ext_vector_type(2)));

__device__ __forceinline__ float bf2f(ushort u){
  union { unsigned int i; float f; } x; x.i = ((unsigned int)u) << 16; return x.f;
}
__device__ __forceinline__ ushort f2bf(float f){
  union { unsigned int i; float f; } x; x.f = f;
  unsigned int i = x.i;
  return (ushort)((i + 0x7FFFu + ((i >> 16) & 1u)) >> 16);   // RNE
}
__device__ __forceinline__ float lo16(unsigned u){
  union { unsigned i; float f; } x; x.i = u << 16; return x.f;
}
__device__ __forceinline__ float hi16(unsigned u){
  union { unsigned i; float f; } x; x.i = u & 0xFFFF0000u; return x.f;
}
__device__ __forceinline__ float sigm(float x){ return 1.0f / (1.0f + expf(-x)); }

// ---------------- fused prep: u-pass x2 | W_in transpose | W_out pass -------
// grid: [0,256) u-pass halves | [256,4352) transpose | [4352,5376) W_out
__global__ __launch_bounds__(256) void k_prep_all(
    const float* __restrict__ u, const float* __restrict__ dlog,
    float* __restrict__ vpart, ushort* __restrict__ U_bf,
    const float* __restrict__ W_in, ushort* __restrict__ WinT,
    const float* __restrict__ Wout, const float* __restrict__ s0,
    const float* __restrict__ b_in, ushort* __restrict__ Wout_bf,
    float* __restrict__ z0, float* __restrict__ cterm){
  const int bid = blockIdx.x;
  const int tid = threadIdx.x;

  if (bid < 256){
    int x = bid >> 1, half = bid & 1;
    int c = x & 31, b = x >> 5;
    int d0 = half*512 + tid*2;
    float p[4];
    #pragma unroll
    for (int k = 0; k < 4; ++k) p[k] = sigm(dlog[k]);
    f32x2 a0 = {0,0}, a1 = {0,0}, a2 = {0,0}, a3 = {0,0};
    size_t ub = ((size_t)(b*Tt + c*LCH)) * Dd + d0;
    for (int i = 0; i < LCH; ++i){
      f32x2 uv = *(const f32x2*)(u + ub);
      ushort2 ob; ob.x = f2bf(uv[0]); ob.y = f2bf(uv[1]);
      *(ushort2*)(U_bf + ub) = ob;
      a0 = p[0]*a0 + uv; a1 = p[1]*a1 + uv; a2 = p[2]*a2 + uv; a3 = p[3]*a3 + uv;
      ub += Dd;
    }
    size_t vb = ((size_t)x * Kk) * Dd + d0;
    *(f32x2*)(vpart + vb)          = a0;
    *(f32x2*)(vpart + vb + Dd)     = a1;
    *(f32x2*)(vpart + vb + 2*Dd)   = a2;
    *(f32x2*)(vpart + vb + 3*Dd)   = a3;
  } else if (bid < 4352){
    __shared__ float tile[32][33];
    int bb = bid - 256;
    int c0 = (bb & 31) * 32, r0 = (bb >> 5) * 32;
    int tx = tid & 31, ty = tid >> 5;     // 32 x 8
    #pragma unroll
    for (int j = 0; j < 4; ++j)
      tile[ty + j*8][tx] = W_in[(size_t)(r0 + ty + j*8) * Dd + c0 + tx];
    __syncthreads();
    #pragma unroll
    for (int j = 0; j < 4; ++j)
      WinT[(size_t)(c0 + ty + j*8) * Ee + r0 + tx] = f2bf(tile[tx][ty + j*8]);
  } else {
    int gid  = (bid - 4352) * 4 + (tid >> 6);   // k*1024 + d
    int lane = tid & 63;
    int d = gid & 1023, k = gid >> 10;
    const float* wrow = Wout + (size_t)d * Ee + k * Dd;
    ushort*      wbf  = Wout_bf + (size_t)d * Ee + k * Dd;
    const float* bv   = b_in + k * Dd;
    float sc = 0.f, sz0 = 0.f, sz1 = 0.f, sz2 = 0.f, sz3 = 0.f;
    #pragma unroll
    for (int j = 0; j < 4; ++j){
      int base = lane*4 + j*256;
      float4 wv = *(const float4*)(wrow + base);
      ushort4 ob; ob.x = f2bf(wv.x); ob.y = f2bf(wv.y); ob.z = f2bf(wv.z); ob.w = f2bf(wv.w);
      *(ushort4*)(wbf + base) = ob;
      float4 bb4 = *(const float4*)(bv + base);
      sc += wv.x*bb4.x + wv.y*bb4.y + wv.z*bb4.z + wv.w*bb4.w;
      #pragma unroll
      for (int b = 0; b < 4; ++b){
        const float* sv = s0 + ((size_t)(b*Kk + k) << 10) + base;
        float4 s4 = *(const float4*)sv;
        float acc = wv.x*s4.x + wv.y*s4.y + wv.z*s4.z + wv.w*s4.w;
        if (b == 0) sz0 += acc; else if (b == 1) sz1 += acc;
        else if (b == 2) sz2 += acc; else sz3 += acc;
      }
    }
    for (int off = 32; off; off >>= 1){
      sc  += __shfl_down(sc, off);
      sz0 += __shfl_down(sz0, off);
      sz1 += __shfl_down(sz1, off);
      sz2 += __shfl_down(sz2, off);
      sz3 += __shfl_down(sz3, off);
    }
    if (lane == 0){
      cterm[gid] = sc;
      z0[gid]          = sz0;
      z0[gid + 4096]   = sz1;
      z0[gid + 8192]   = sz2;
      z0[gid + 12288]  = sz3;
    }
  }
}

// ---------------- small NT GEMM (m97 structure) for Mcat --------------------
__global__ __launch_bounds__(256) void gemm_nt(const ushort* __restrict__ A,
                                               const ushort* __restrict__ B,
                                               ushort* __restrict__ C,
                                               int Kred, int lda, int ldb, int ldc,
                                               long aBatch, long bBatch, long cBatch){
  __shared__ ushort As[128 * 32];
  __shared__ ushort Bs[128 * 32];
  A += (long)blockIdx.z * aBatch;
  B += (long)blockIdx.z * bBatch;
  C += (long)blockIdx.z * cBatch;
  const int tid  = threadIdx.x;
  const int lane = tid & 63;
  const int w    = tid >> 6;
  const int wr   = w >> 1, wc = w & 1;
  const int rowBase = blockIdx.x * 128;
  const int colBase = blockIdx.y * 128;

  f32x4 acc[4][4] = {};
  const int krow = (lane >> 4) * 8;
  const int rsel = lane & 15;

  for (int kk = 0; kk < Kred; kk += 32){
    __syncthreads();
    #pragma unroll
    for (int i = 0; i < 2; ++i){
      int c  = i * 256 + tid;
      int r  = c >> 2;
      int c8 = (c & 3) * 8;
      const ushort* ga = A + (size_t)(rowBase + r) * lda + kk + c8;
      const ushort* gb = B + (size_t)(colBase + r) * ldb + kk + c8;
      __builtin_amdgcn_global_load_lds((const __attribute__((address_space(1))) void*)ga,
                                       (__attribute__((address_space(3))) void*)&As[c * 8],
                                       16, 0, 0);
      __builtin_amdgcn_global_load_lds((const __attribute__((address_space(1))) void*)gb,
                                       (__attribute__((address_space(3))) void*)&Bs[c * 8],
                                       16, 0, 0);
    }
    asm volatile("s_waitcnt vmcnt(0)" ::: "memory");
    __syncthreads();

    bf16x8 Af[4], Bf[4];
    #pragma unroll
    for (int mi = 0; mi < 4; ++mi)
      Af[mi] = *(const bf16x8*)&As[(wr*64 + mi*16 + rsel) * 32 + krow];
    #pragma unroll
    for (int ni = 0; ni < 4; ++ni)
      Bf[ni] = *(const bf16x8*)&Bs[(wc*64 + ni*16 + rsel) * 32 + krow];
    #pragma unroll
    for (int mi = 0; mi < 4; ++mi)
      #pragma unroll
      for (int ni = 0; ni < 4; ++ni)
        acc[mi][ni] = __builtin_amdgcn_mfma_f32_16x16x32_bf16(Af[mi], Bf[ni], acc[mi][ni], 0, 0, 0);
  }

  #pragma unroll
  for (int mi = 0; mi < 4; ++mi){
    #pragma unroll
    for (int ni = 0; ni < 4; ++ni){
      int r0 = rowBase + wr*64 + mi*16 + (lane >> 4) * 4;
      int c0 = colBase + wc*64 + ni*16 + (lane & 15);
      #pragma unroll
      for (int q = 0; q < 4; ++q)
        C[(size_t)(r0 + q) * ldc + c0] = f2bf(acc[mi][ni][q]);
    }
  }
}

// ---------------- gemm_big: Y = U_bf @ Mcat^T, 128x256 block, 3 blk/CU ------
// LDS: buf c @ c*12288 ushorts {A [128][32] @0, B [256][32] @4096}. 48KB dbuf.
#define STAGE_A(GB, LOFF)                                                      \
  { _Pragma("unroll")                                                          \
    for (int i_ = 0; i_ < 2; ++i_){                                            \
      int c_ = tid + i_*256;                                                   \
      int row_ = c_ >> 2;                                                      \
      int ss_ = (c_ & 3) ^ ((row_ >> 1) & 3);                                  \
      const ushort* g_ = (GB) + (size_t)row_ * 1024 + ss_ * 8;                 \
      __builtin_amdgcn_global_load_lds(                                        \
        (const __attribute__((address_space(1))) void*)g_,                     \
        (__attribute__((address_space(3))) void*)&lds[(LOFF) + c_*8],          \
        16, 0, 0);                                                             \
    } }

#define STAGE_B(GB, LOFF)                                                      \
  { _Pragma("unroll")                                                          \
    for (int i_ = 0; i_ < 4; ++i_){                                            \
      int c_ = tid + i_*256;                                                   \
      int row_ = c_ >> 2;                                                      \
      int ss_ = (c_ & 3) ^ ((row_ >> 1) & 3);                                  \
      const ushort* g_ = (GB) + (size_t)row_ * 1024 + ss_ * 8;                 \
      __builtin_amdgcn_global_load_lds(                                        \
        (const __attribute__((address_space(1))) void*)g_,                     \
        (__attribute__((address_space(3))) void*)&lds[(LOFF) + 4096 + c_*8],   \
        16, 0, 0);                                                             \
    } }

#define LOAD_A4(DST)                                                           \
  { _Pragma("unroll")                                                          \
    for (int mi_ = 0; mi_ < 4; ++mi_){                                         \
      int r_ = wm*64 + mi_*16 + rsel;                                          \
      int uo_ = r_*32 + kq*8;                                                  \
      uo_ ^= ((uo_ >> 6) & 3) << 3;                                            \
      DST[mi_] = *(const bf16x8*)&lds[cbase + uo_];                            \
    } }

#define LOAD_B8(DST)                                                           \
  { _Pragma("unroll")                                                          \
    for (int ni_ = 0; ni_ < 8; ++ni_){                                         \
      int r_ = wn*128 + ni_*16 + rsel;                                         \
      int uo_ = r_*32 + kq*8;                                                  \
      uo_ ^= ((uo_ >> 6) & 3) << 3;                                            \
      DST[ni_] = *(const bf16x8*)&lds[cbase + 4096 + uo_];                     \
    } }

#define XB(R) ((((R) & 3) ^ (((R) >> 2) & 3)) << 5)
#define BAR() __builtin_amdgcn_s_barrier()

__global__ __launch_bounds__(256, 3) void gemm_big(const ushort* __restrict__ A,
                                                   const ushort* __restrict__ B,
                                                   ushort* __restrict__ C,
                                                   const float* __restrict__ dlog,
                                                   float* __restrict__ carry){
  __shared__ ushort lds[24576];       // 48 KB dbuf -> 3 blocks/CU (144KB)
  const int tid  = threadIdx.x;
  const int lane = tid & 63;
  const int w    = tid >> 6;          // 0..3
  const int wm   = w >> 1;            // 2 M-waves
  const int wn   = w & 1;             // 2 N-waves (128-col strips)
  const int rsel = lane & 15;
  const int kq   = lane >> 4;

  // grid 1024 = 64M x 16N tiles; XCD region 8M x 16N.
  int bid = blockIdx.x;
  int xcd = bid & 7, rr = bid >> 3;   // rr 0..127
  const int rowBase = (xcd * 8 + (rr & 7)) * 128;   // 64 M-tiles (bt)
  const int colBase = (rr >> 3) * 256;              // 16 N-tiles (Y cols)

  const ushort* Ag = A + (size_t)rowBase * 1024;
  const ushort* Bg = B + (size_t)colBase * 1024;

  f32x4 acc[4][8] = {};

  // prologue: tile0 -> buf0, tile1 -> buf1 (6 loads/thread each)
  STAGE_A(Ag +  0, 0);
  STAGE_B(Bg +  0, 0);
  STAGE_A(Ag + 32, 12288);
  STAGE_B(Bg + 32, 12288);
  asm volatile("s_waitcnt vmcnt(6)" ::: "memory");   // tile0 landed
  BAR();

  for (int t = 0; t < 32; ++t){
    const int cbase = (t & 1) * 12288;
    bf16x8 af[4], bf[8];
    LOAD_A4(af); LOAD_B8(bf);
    #pragma unroll
    for (int mi = 0; mi < 4; ++mi)
      #pragma unroll
      for (int ni = 0; ni < 8; ++ni)
        acc[mi][ni] = __builtin_amdgcn_mfma_f32_16x16x32_bf16(af[mi], bf[ni], acc[mi][ni], 0, 0, 0);
    asm volatile("s_waitcnt lgkmcnt(0)" ::: "memory");
    BAR();
    if (t < 30){
      STAGE_A(Ag + (t+2)*32, cbase);
      STAGE_B(Bg + (t+2)*32, cbase);
      asm volatile("s_waitcnt vmcnt(6)" ::: "memory");   // tile t+1 landed
    } else {
      asm volatile("s_waitcnt vmcnt(0)" ::: "memory");
    }
    BAR();
  }

  // ---- epilogue: two 128-col halves; each = R12's proven machinery.
  #pragma unroll
  for (int h = 0; h < 2; ++h){
    if (wn == h){
      #pragma unroll
      for (int mi = 0; mi < 4; ++mi){
        #pragma unroll
        for (int ni = 0; ni < 8; ++ni){
          #pragma unroll
          for (int q = 0; q < 4; ++q){
            int row = wm*64 + mi*16 + (lane >> 4)*4 + q;
            int col = ni*16 + rsel;
            int byte = (row*256 + col*2) ^ XB(row);
            *(ushort*)((char*)lds + byte) = f2bf(acc[mi][ni][q]);
          }
        }
      }
    }
    __syncthreads();

    const int colH = colBase + h*128;
    // fused scanA carries: 2 chunks x 64 col-pairs -> threads 0..127
    if (tid < 128){
      const int k_blk = colH >> 10;
      const int b_blk = rowBase >> 11;
      const int ch0   = (rowBase & 2047) >> 6;
      const int d0    = colH & 1023;
      const float p   = sigm(dlog[k_blk]);
      int cp = tid & 63, ch = tid >> 6;
      float a0 = 0.f, a1 = 0.f;
      for (int i = 0; i < 64; ++i){
        int row = ch*64 + i;
        int byte = (row*256 + cp*4) ^ XB(row);
        unsigned v = *(const unsigned*)((char*)lds + byte);
        a0 = p * a0 + lo16(v);
        a1 = p * a1 + hi16(v);
      }
      float* cdst = &carry[(size_t)((b_blk*Kk + k_blk)*NCH + ch0 + ch) * Dd + d0 + cp*2];
      cdst[0] = a0; cdst[1] = a1;
    }

    // coalesced Y write: 16B per lane, 8 sweeps
    #pragma unroll
    for (int j = 0; j < 8; ++j){
      int idx = tid + j*256;
      int r = idx >> 4, c16 = idx & 15;
      int byte = (r*256 + c16*16) ^ XB(r);
      f32x4 v = *(const f32x4*)((char*)lds + byte);
      *(f32x4*)&C[(size_t)(rowBase + r) * Ee + colH + c16*8] = v;
    }
    __syncthreads();
  }
}

// ---------------- fused mid: scanInc | vcomb --------------------------------
__global__ __launch_bounds__(256) void k_mid(const float* __restrict__ carry,
                                             const float* __restrict__ z0,
                                             const float* __restrict__ dlog,
                                             float* __restrict__ incoming,
                                             const float* __restrict__ vpart,
                                             float* __restrict__ vfull){
  int bid = blockIdx.x, tid = threadIdx.x;
  if (bid < 64){
    int idx = bid * 256 + tid;
    int k = (idx >> 10) & 3;
    int bk = idx >> 10, d = idx & 1023;
    float p  = sigm(dlog[k]);
    float dL = powf(p, (float)LCH);
    float inc = z0[idx];
    for (int c = 0; c < NCH; ++c){
      size_t o = ((size_t)(bk * NCH + c)) * Dd + d;
      incoming[o] = inc;
      inc = dL * inc + carry[o];
    }
  } else {
    int idx = (bid - 64) * 256 + tid;
    int k = (idx >> 10) & 3, b = idx >> 12, d = idx & 1023;
    float p  = sigm(dlog[k]);
    float dL = powf(p, (float)LCH);
    float v = 0.f;
    for (int c = 0; c < NCH; ++c)
      v = dL * v + vpart[(((size_t)(b*NCH + c)) * Kk + k) * Dd + d];
    vfull[idx] = v;
  }
}

// ---------------- fused final: scanB (4 d/thread, uint2) | slast ------------
__global__ __launch_bounds__(256) void k_final(const ushort* __restrict__ Y,
                                               const float* __restrict__ incoming,
                                               const float* __restrict__ dlog,
                                               const float* __restrict__ b_out,
                                               const float* __restrict__ cterm,
                                               float* __restrict__ g,
                                               const float* __restrict__ W_in,
                                               const float* __restrict__ vfull,
                                               const float* __restrict__ s0,
                                               const float* __restrict__ b_in,
                                               float* __restrict__ slast){
  int bid = blockIdx.x, tid = threadIdx.x;
  if (bid < 128){
    // scanB: x = bid (b*NCH+c), d = tid*4 (4 consecutive d per thread)
    int x = bid;
    int c = x & 31, b = x >> 5;
    int d = tid * 4;
    float p[4], pw[4];
    float zv[4][4], ct[4][4];
    #pragma unroll
    for (int k = 0; k < 4; ++k){
      p[k]  = sigm(dlog[k]);
      size_t io = ((size_t)(((b*Kk + k))*NCH + c)) * Dd + d;
      #pragma unroll
      for (int j = 0; j < 4; ++j) zv[k][j] = incoming[io + j];
      float omp = fmaxf(1.0f - p[k], 1e-30f);
      #pragma unroll
      for (int j = 0; j < 4; ++j) ct[k][j] = cterm[k * Dd + d + j] / omp;
      pw[k] = powf(p[k], (float)(c * LCH + 1));
    }
    float bo[4];
    #pragma unroll
    for (int j = 0; j < 4; ++j) bo[j] = b_out[d + j];
    size_t ybase = ((size_t)(b*Tt + c*LCH)) * Ee + d;
    size_t gbase = ((size_t)(b*Tt + c*LCH)) * Dd + d;
    for (int i = 0; i < LCH; ++i){
      f32x4 accv = {bo[0], bo[1], bo[2], bo[3]};
      #pragma unroll
      for (int k = 0; k < 4; ++k){
        uint2 yv = *(const uint2*)&Y[ybase + (size_t)k * Dd];
        float y0 = lo16(yv.x), y1 = hi16(yv.x), y2 = lo16(yv.y), y3 = hi16(yv.y);
        zv[k][0] = p[k]*zv[k][0] + y0;
        zv[k][1] = p[k]*zv[k][1] + y1;
        zv[k][2] = p[k]*zv[k][2] + y2;
        zv[k][3] = p[k]*zv[k][3] + y3;
        float omw = 1.0f - pw[k];
        accv[0] += zv[k][0] + ct[k][0]*omw;
        accv[1] += zv[k][1] + ct[k][1]*omw;
        accv[2] += zv[k][2] + ct[k][2]*omw;
        accv[3] += zv[k][3] + ct[k][3]*omw;
        pw[k] *= p[k];
      }
      *(f32x4*)&g[gbase] = accv;
      ybase += Ee; gbase += Dd;
    }
  } else {
    int gid  = (bid - 128) * 4 + (tid >> 6);
    int lane = tid & 63;
    int d = gid & 1023, k = (gid >> 10) & 3, b = gid >> 12;
    const float* wrow = W_in + (size_t)(k*Dd + d) * Dd;
    const float* vv   = vfull + ((size_t)(b*Kk + k) << 10);
    float s = 0.f;
    #pragma unroll
    for (int j = 0; j < 4; ++j){
      int base = lane*4 + j*256;
      float4 w4 = *(const float4*)(wrow + base);
      float4 v4 = *(const float4*)(vv + base);
      s += w4.x*v4.x + w4.y*v4.y + w4.z*v4.z + w4.w*v4.w;
    }
    for (int off = 32; off; off >>= 1) s += __shfl_down(s, off);
    if (lane == 0){
      float p  = sigm(dlog[k]);
      float pT = powf(p, (float)Tt);
      float omp = 1.0f - p;
      float geo = (omp < 1e-12f) ? (float)Tt : (1.0f - pT) / omp;
      slast[gid] = pT * s0[gid] + s + b_in[k*Dd + d] * geo;
    }
  }
}

// ---------------------------------------------------------------------------
extern "C" void kernel_launch(void* const* d_in, const int* in_sizes, int n_in,
                              void* d_out, int out_size, void* d_ws, size_t ws_size,
                              hipStream_t stream){
  const float* u     = (const float*)d_in[0];
  const float* s0    = (const float*)d_in[1];
  const float* W_in  = (const float*)d_in[2];
  const float* b_in  = (const float*)d_in[3];
  const float* W_out = (const float*)d_in[4];
  const float* b_out = (const float*)d_in[5];
  const float* dlog  = (const float*)d_in[6];

  float* g_out     = (float*)d_out;                      // B*T*D
  float* slast_out = g_out + (size_t)BT * Dd;            // B*K*D

  char* ws = (char*)d_ws;
  if (ws_size < 115490816ull) return;
  ushort* U_bf    = (ushort*)(ws);                       // 16 MB
  ushort* WinT    = (ushort*)(ws + 16777216);            //  8 MB
  ushort* Wout_bf = (ushort*)(ws + 25165824);            //  8 MB
  ushort* Mcat    = (ushort*)(ws + 33554432);            //  8 MB
  ushort* Y       = (ushort*)(ws + 41943040);            // 64 MB
  float*  carry   = (float*)(ws + 109051904);            //  2 MB
  float*  incoming= (float*)(ws + 111149056);            //  2 MB
  float*  z0buf   = (float*)(ws + 113246208);            // 64 KB
  float*  cterm   = (float*)(ws + 113311744);            // 16 KB
  float*  vpart   = (float*)(ws + 113328128);            //  2 MB
  float*  vfull   = (float*)(ws + 115425280);            // 64 KB

  // 1) fused prep
  k_prep_all<<<5376, 256, 0, stream>>>(u, dlog, vpart, U_bf,
                                       W_in, WinT,
                                       W_out, s0, b_in, Wout_bf, z0buf, cterm);

  // 2) Mcat[(k,d), d'] = sum_j Wout[d, kD+j] * WinT[d', kD+j]
  gemm_nt<<<dim3(8, 8, 4), 256, 0, stream>>>(Wout_bf, WinT, Mcat,
                                             1024, Ee, Ee, Dd,
                                             1024L, 1024L, 1048576L);
  // 3) Y = U @ Mcat^T + fused chunk carries (3 blocks/CU)
  gemm_big<<<1024, 256, 0, stream>>>(U_bf, Mcat, Y, dlog, carry);

  // 4) fused mid: scanInc [0,64) | vcomb [64,128)
  k_mid<<<128, 256, 0, stream>>>(carry, z0buf, dlog, incoming, vpart, vfull);

  // 5) fused final: scanB [0,128) | slast [128,4224)
  k_final<<<4224, 256, 0, stream>>>(Y, incoming, dlog, b_out, cterm, g_out,
                                    W_in, vfull, s0, b_in, slast_out);
}

// Round 18
// 154.958 us; speedup vs baseline: 2.0846x; 2.0846x over previous
//
#include <hip/hip_runtime.h>

// ---------------------------------------------------------------------------
// StateBank R18 = best-known combination:
//   gemm_big: R15/R16 config (128x256 block, wide waves af[4]/bf[8], BK=32,
//   48KB dbuf, launch_bounds(256,2) — R17's (256,3) caused acc spill:
//   VGPR 128->84, WRITE 67->451MB, 301us. 2 blk/CU is the VGPR max here.)
//   aux: R17's scanB (4 d/thread, uint2) + u-pass (256 blocks) kept.
// ---------------------------------------------------------------------------

#define Bb 4
#define Tt 2048
#define Dd 1024
#define Kk 4
#define BT (Bb*Tt)          // 8192
#define Ee (Kk*Dd)          // 4096
#define NCH 32              // scan chunks
#define LCH 64              // chunk length (NCH*LCH = T)

typedef __bf16 bf16x8 __attribute__((ext_vector_type(8)));
typedef float  f32x4  __attribute__((ext_vector_type(4)));
typedef float  f32x2  __attribute__((ext_vector_type(2)));

__device__ __forceinline__ float bf2f(ushort u){
  union { unsigned int i; float f; } x; x.i = ((unsigned int)u) << 16; return x.f;
}
__device__ __forceinline__ ushort f2bf(float f){
  union { unsigned int i; float f; } x; x.f = f;
  unsigned int i = x.i;
  return (ushort)((i + 0x7FFFu + ((i >> 16) & 1u)) >> 16);   // RNE
}
__device__ __forceinline__ float lo16(unsigned u){
  union { unsigned i; float f; } x; x.i = u << 16; return x.f;
}
__device__ __forceinline__ float hi16(unsigned u){
  union { unsigned i; float f; } x; x.i = u & 0xFFFF0000u; return x.f;
}
__device__ __forceinline__ float sigm(float x){ return 1.0f / (1.0f + expf(-x)); }

// ---------------- fused prep: u-pass x2 | W_in transpose | W_out pass -------
// grid: [0,256) u-pass halves | [256,4352) transpose | [4352,5376) W_out
__global__ __launch_bounds__(256) void k_prep_all(
    const float* __restrict__ u, const float* __restrict__ dlog,
    float* __restrict__ vpart, ushort* __restrict__ U_bf,
    const float* __restrict__ W_in, ushort* __restrict__ WinT,
    const float* __restrict__ Wout, const float* __restrict__ s0,
    const float* __restrict__ b_in, ushort* __restrict__ Wout_bf,
    float* __restrict__ z0, float* __restrict__ cterm){
  const int bid = blockIdx.x;
  const int tid = threadIdx.x;

  if (bid < 256){
    int x = bid >> 1, half = bid & 1;
    int c = x & 31, b = x >> 5;
    int d0 = half*512 + tid*2;
    float p[4];
    #pragma unroll
    for (int k = 0; k < 4; ++k) p[k] = sigm(dlog[k]);
    f32x2 a0 = {0,0}, a1 = {0,0}, a2 = {0,0}, a3 = {0,0};
    size_t ub = ((size_t)(b*Tt + c*LCH)) * Dd + d0;
    for (int i = 0; i < LCH; ++i){
      f32x2 uv = *(const f32x2*)(u + ub);
      ushort2 ob; ob.x = f2bf(uv[0]); ob.y = f2bf(uv[1]);
      *(ushort2*)(U_bf + ub) = ob;
      a0 = p[0]*a0 + uv; a1 = p[1]*a1 + uv; a2 = p[2]*a2 + uv; a3 = p[3]*a3 + uv;
      ub += Dd;
    }
    size_t vb = ((size_t)x * Kk) * Dd + d0;
    *(f32x2*)(vpart + vb)          = a0;
    *(f32x2*)(vpart + vb + Dd)     = a1;
    *(f32x2*)(vpart + vb + 2*Dd)   = a2;
    *(f32x2*)(vpart + vb + 3*Dd)   = a3;
  } else if (bid < 4352){
    __shared__ float tile[32][33];
    int bb = bid - 256;
    int c0 = (bb & 31) * 32, r0 = (bb >> 5) * 32;
    int tx = tid & 31, ty = tid >> 5;     // 32 x 8
    #pragma unroll
    for (int j = 0; j < 4; ++j)
      tile[ty + j*8][tx] = W_in[(size_t)(r0 + ty + j*8) * Dd + c0 + tx];
    __syncthreads();
    #pragma unroll
    for (int j = 0; j < 4; ++j)
      WinT[(size_t)(c0 + ty + j*8) * Ee + r0 + tx] = f2bf(tile[tx][ty + j*8]);
  } else {
    int gid  = (bid - 4352) * 4 + (tid >> 6);   // k*1024 + d
    int lane = tid & 63;
    int d = gid & 1023, k = gid >> 10;
    const float* wrow = Wout + (size_t)d * Ee + k * Dd;
    ushort*      wbf  = Wout_bf + (size_t)d * Ee + k * Dd;
    const float* bv   = b_in + k * Dd;
    float sc = 0.f, sz0 = 0.f, sz1 = 0.f, sz2 = 0.f, sz3 = 0.f;
    #pragma unroll
    for (int j = 0; j < 4; ++j){
      int base = lane*4 + j*256;
      float4 wv = *(const float4*)(wrow + base);
      ushort4 ob; ob.x = f2bf(wv.x); ob.y = f2bf(wv.y); ob.z = f2bf(wv.z); ob.w = f2bf(wv.w);
      *(ushort4*)(wbf + base) = ob;
      float4 bb4 = *(const float4*)(bv + base);
      sc += wv.x*bb4.x + wv.y*bb4.y + wv.z*bb4.z + wv.w*bb4.w;
      #pragma unroll
      for (int b = 0; b < 4; ++b){
        const float* sv = s0 + ((size_t)(b*Kk + k) << 10) + base;
        float4 s4 = *(const float4*)sv;
        float acc = wv.x*s4.x + wv.y*s4.y + wv.z*s4.z + wv.w*s4.w;
        if (b == 0) sz0 += acc; else if (b == 1) sz1 += acc;
        else if (b == 2) sz2 += acc; else sz3 += acc;
      }
    }
    for (int off = 32; off; off >>= 1){
      sc  += __shfl_down(sc, off);
      sz0 += __shfl_down(sz0, off);
      sz1 += __shfl_down(sz1, off);
      sz2 += __shfl_down(sz2, off);
      sz3 += __shfl_down(sz3, off);
    }
    if (lane == 0){
      cterm[gid] = sc;
      z0[gid]          = sz0;
      z0[gid + 4096]   = sz1;
      z0[gid + 8192]   = sz2;
      z0[gid + 12288]  = sz3;
    }
  }
}

// ---------------- small NT GEMM (m97 structure) for Mcat --------------------
__global__ __launch_bounds__(256) void gemm_nt(const ushort* __restrict__ A,
                                               const ushort* __restrict__ B,
                                               ushort* __restrict__ C,
                                               int Kred, int lda, int ldb, int ldc,
                                               long aBatch, long bBatch, long cBatch){
  __shared__ ushort As[128 * 32];
  __shared__ ushort Bs[128 * 32];
  A += (long)blockIdx.z * aBatch;
  B += (long)blockIdx.z * bBatch;
  C += (long)blockIdx.z * cBatch;
  const int tid  = threadIdx.x;
  const int lane = tid & 63;
  const int w    = tid >> 6;
  const int wr   = w >> 1, wc = w & 1;
  const int rowBase = blockIdx.x * 128;
  const int colBase = blockIdx.y * 128;

  f32x4 acc[4][4] = {};
  const int krow = (lane >> 4) * 8;
  const int rsel = lane & 15;

  for (int kk = 0; kk < Kred; kk += 32){
    __syncthreads();
    #pragma unroll
    for (int i = 0; i < 2; ++i){
      int c  = i * 256 + tid;
      int r  = c >> 2;
      int c8 = (c & 3) * 8;
      const ushort* ga = A + (size_t)(rowBase + r) * lda + kk + c8;
      const ushort* gb = B + (size_t)(colBase + r) * ldb + kk + c8;
      __builtin_amdgcn_global_load_lds((const __attribute__((address_space(1))) void*)ga,
                                       (__attribute__((address_space(3))) void*)&As[c * 8],
                                       16, 0, 0);
      __builtin_amdgcn_global_load_lds((const __attribute__((address_space(1))) void*)gb,
                                       (__attribute__((address_space(3))) void*)&Bs[c * 8],
                                       16, 0, 0);
    }
    asm volatile("s_waitcnt vmcnt(0)" ::: "memory");
    __syncthreads();

    bf16x8 Af[4], Bf[4];
    #pragma unroll
    for (int mi = 0; mi < 4; ++mi)
      Af[mi] = *(const bf16x8*)&As[(wr*64 + mi*16 + rsel) * 32 + krow];
    #pragma unroll
    for (int ni = 0; ni < 4; ++ni)
      Bf[ni] = *(const bf16x8*)&Bs[(wc*64 + ni*16 + rsel) * 32 + krow];
    #pragma unroll
    for (int mi = 0; mi < 4; ++mi)
      #pragma unroll
      for (int ni = 0; ni < 4; ++ni)
        acc[mi][ni] = __builtin_amdgcn_mfma_f32_16x16x32_bf16(Af[mi], Bf[ni], acc[mi][ni], 0, 0, 0);
  }

  #pragma unroll
  for (int mi = 0; mi < 4; ++mi){
    #pragma unroll
    for (int ni = 0; ni < 4; ++ni){
      int r0 = rowBase + wr*64 + mi*16 + (lane >> 4) * 4;
      int c0 = colBase + wc*64 + ni*16 + (lane & 15);
      #pragma unroll
      for (int q = 0; q < 4; ++q)
        C[(size_t)(r0 + q) * ldc + c0] = f2bf(acc[mi][ni][q]);
    }
  }
}

// ---------------- gemm_big: Y = U_bf @ Mcat^T, 128x256 block, 2 blk/CU ------
// LDS: buf c @ c*12288 ushorts {A [128][32] @0, B [256][32] @4096}. 48KB dbuf.
#define STAGE_A(GB, LOFF)                                                      \
  { _Pragma("unroll")                                                          \
    for (int i_ = 0; i_ < 2; ++i_){                                            \
      int c_ = tid + i_*256;                                                   \
      int row_ = c_ >> 2;                                                      \
      int ss_ = (c_ & 3) ^ ((row_ >> 1) & 3);                                  \
      const ushort* g_ = (GB) + (size_t)row_ * 1024 + ss_ * 8;                 \
      __builtin_amdgcn_global_load_lds(                                        \
        (const __attribute__((address_space(1))) void*)g_,                     \
        (__attribute__((address_space(3))) void*)&lds[(LOFF) + c_*8],          \
        16, 0, 0);                                                             \
    } }

#define STAGE_B(GB, LOFF)                                                      \
  { _Pragma("unroll")                                                          \
    for (int i_ = 0; i_ < 4; ++i_){                                            \
      int c_ = tid + i_*256;                                                   \
      int row_ = c_ >> 2;                                                      \
      int ss_ = (c_ & 3) ^ ((row_ >> 1) & 3);                                  \
      const ushort* g_ = (GB) + (size_t)row_ * 1024 + ss_ * 8;                 \
      __builtin_amdgcn_global_load_lds(                                        \
        (const __attribute__((address_space(1))) void*)g_,                     \
        (__attribute__((address_space(3))) void*)&lds[(LOFF) + 4096 + c_*8],   \
        16, 0, 0);                                                             \
    } }

#define LOAD_A4(DST)                                                           \
  { _Pragma("unroll")                                                          \
    for (int mi_ = 0; mi_ < 4; ++mi_){                                         \
      int r_ = wm*64 + mi_*16 + rsel;                                          \
      int uo_ = r_*32 + kq*8;                                                  \
      uo_ ^= ((uo_ >> 6) & 3) << 3;                                            \
      DST[mi_] = *(const bf16x8*)&lds[cbase + uo_];                            \
    } }

#define LOAD_B8(DST)                                                           \
  { _Pragma("unroll")                                                          \
    for (int ni_ = 0; ni_ < 8; ++ni_){                                         \
      int r_ = wn*128 + ni_*16 + rsel;                                         \
      int uo_ = r_*32 + kq*8;                                                  \
      uo_ ^= ((uo_ >> 6) & 3) << 3;                                            \
      DST[ni_] = *(const bf16x8*)&lds[cbase + 4096 + uo_];                     \
    } }

#define XB(R) ((((R) & 3) ^ (((R) >> 2) & 3)) << 5)
#define BAR() __builtin_amdgcn_s_barrier()

__global__ __launch_bounds__(256, 2) void gemm_big(const ushort* __restrict__ A,
                                                   const ushort* __restrict__ B,
                                                   ushort* __restrict__ C,
                                                   const float* __restrict__ dlog,
                                                   float* __restrict__ carry){
  __shared__ ushort lds[24576];       // 48 KB dbuf -> 2 blocks/CU
  const int tid  = threadIdx.x;
  const int lane = tid & 63;
  const int w    = tid >> 6;          // 0..3
  const int wm   = w >> 1;            // 2 M-waves
  const int wn   = w & 1;             // 2 N-waves (128-col strips)
  const int rsel = lane & 15;
  const int kq   = lane >> 4;

  // grid 1024 = 64M x 16N tiles; XCD region 8M x 16N.
  int bid = blockIdx.x;
  int xcd = bid & 7, rr = bid >> 3;   // rr 0..127
  const int rowBase = (xcd * 8 + (rr & 7)) * 128;   // 64 M-tiles (bt)
  const int colBase = (rr >> 3) * 256;              // 16 N-tiles (Y cols)

  const ushort* Ag = A + (size_t)rowBase * 1024;
  const ushort* Bg = B + (size_t)colBase * 1024;

  f32x4 acc[4][8] = {};

  // prologue: tile0 -> buf0, tile1 -> buf1 (6 loads/thread each)
  STAGE_A(Ag +  0, 0);
  STAGE_B(Bg +  0, 0);
  STAGE_A(Ag + 32, 12288);
  STAGE_B(Bg + 32, 12288);
  asm volatile("s_waitcnt vmcnt(6)" ::: "memory");   // tile0 landed
  BAR();

  for (int t = 0; t < 32; ++t){
    const int cbase = (t & 1) * 12288;
    bf16x8 af[4], bf[8];
    LOAD_A4(af); LOAD_B8(bf);
    #pragma unroll
    for (int mi = 0; mi < 4; ++mi)
      #pragma unroll
      for (int ni = 0; ni < 8; ++ni)
        acc[mi][ni] = __builtin_amdgcn_mfma_f32_16x16x32_bf16(af[mi], bf[ni], acc[mi][ni], 0, 0, 0);
    asm volatile("s_waitcnt lgkmcnt(0)" ::: "memory");
    BAR();
    if (t < 30){
      STAGE_A(Ag + (t+2)*32, cbase);
      STAGE_B(Bg + (t+2)*32, cbase);
      asm volatile("s_waitcnt vmcnt(6)" ::: "memory");   // tile t+1 landed
    } else {
      asm volatile("s_waitcnt vmcnt(0)" ::: "memory");
    }
    BAR();
  }

  // ---- epilogue: two 128-col halves; each = R12's proven machinery.
  #pragma unroll
  for (int h = 0; h < 2; ++h){
    if (wn == h){
      #pragma unroll
      for (int mi = 0; mi < 4; ++mi){
        #pragma unroll
        for (int ni = 0; ni < 8; ++ni){
          #pragma unroll
          for (int q = 0; q < 4; ++q){
            int row = wm*64 + mi*16 + (lane >> 4)*4 + q;
            int col = ni*16 + rsel;
            int byte = (row*256 + col*2) ^ XB(row);
            *(ushort*)((char*)lds + byte) = f2bf(acc[mi][ni][q]);
          }
        }
      }
    }
    __syncthreads();

    const int colH = colBase + h*128;
    // fused scanA carries: 2 chunks x 64 col-pairs -> threads 0..127
    if (tid < 128){
      const int k_blk = colH >> 10;
      const int b_blk = rowBase >> 11;
      const int ch0   = (rowBase & 2047) >> 6;
      const int d0    = colH & 1023;
      const float p   = sigm(dlog[k_blk]);
      int cp = tid & 63, ch = tid >> 6;
      float a0 = 0.f, a1 = 0.f;
      for (int i = 0; i < 64; ++i){
        int row = ch*64 + i;
        int byte = (row*256 + cp*4) ^ XB(row);
        unsigned v = *(const unsigned*)((char*)lds + byte);
        a0 = p * a0 + lo16(v);
        a1 = p * a1 + hi16(v);
      }
      float* cdst = &carry[(size_t)((b_blk*Kk + k_blk)*NCH + ch0 + ch) * Dd + d0 + cp*2];
      cdst[0] = a0; cdst[1] = a1;
    }

    // coalesced Y write: 16B per lane, 8 sweeps
    #pragma unroll
    for (int j = 0; j < 8; ++j){
      int idx = tid + j*256;
      int r = idx >> 4, c16 = idx & 15;
      int byte = (r*256 + c16*16) ^ XB(r);
      f32x4 v = *(const f32x4*)((char*)lds + byte);
      *(f32x4*)&C[(size_t)(rowBase + r) * Ee + colH + c16*8] = v;
    }
    __syncthreads();
  }
}

// ---------------- fused mid: scanInc | vcomb --------------------------------
__global__ __launch_bounds__(256) void k_mid(const float* __restrict__ carry,
                                             const float* __restrict__ z0,
                                             const float* __restrict__ dlog,
                                             float* __restrict__ incoming,
                                             const float* __restrict__ vpart,
                                             float* __restrict__ vfull){
  int bid = blockIdx.x, tid = threadIdx.x;
  if (bid < 64){
    int idx = bid * 256 + tid;
    int k = (idx >> 10) & 3;
    int bk = idx >> 10, d = idx & 1023;
    float p  = sigm(dlog[k]);
    float dL = powf(p, (float)LCH);
    float inc = z0[idx];
    for (int c = 0; c < NCH; ++c){
      size_t o = ((size_t)(bk * NCH + c)) * Dd + d;
      incoming[o] = inc;
      inc = dL * inc + carry[o];
    }
  } else {
    int idx = (bid - 64) * 256 + tid;
    int k = (idx >> 10) & 3, b = idx >> 12, d = idx & 1023;
    float p  = sigm(dlog[k]);
    float dL = powf(p, (float)LCH);
    float v = 0.f;
    for (int c = 0; c < NCH; ++c)
      v = dL * v + vpart[(((size_t)(b*NCH + c)) * Kk + k) * Dd + d];
    vfull[idx] = v;
  }
}

// ---------------- fused final: scanB (4 d/thread, uint2) | slast ------------
__global__ __launch_bounds__(256) void k_final(const ushort* __restrict__ Y,
                                               const float* __restrict__ incoming,
                                               const float* __restrict__ dlog,
                                               const float* __restrict__ b_out,
                                               const float* __restrict__ cterm,
                                               float* __restrict__ g,
                                               const float* __restrict__ W_in,
                                               const float* __restrict__ vfull,
                                               const float* __restrict__ s0,
                                               const float* __restrict__ b_in,
                                               float* __restrict__ slast){
  int bid = blockIdx.x, tid = threadIdx.x;
  if (bid < 128){
    // scanB: x = bid (b*NCH+c), d = tid*4 (4 consecutive d per thread)
    int x = bid;
    int c = x & 31, b = x >> 5;
    int d = tid * 4;
    float p[4], pw[4];
    float zv[4][4], ct[4][4];
    #pragma unroll
    for (int k = 0; k < 4; ++k){
      p[k]  = sigm(dlog[k]);
      size_t io = ((size_t)(((b*Kk + k))*NCH + c)) * Dd + d;
      #pragma unroll
      for (int j = 0; j < 4; ++j) zv[k][j] = incoming[io + j];
      float omp = fmaxf(1.0f - p[k], 1e-30f);
      #pragma unroll
      for (int j = 0; j < 4; ++j) ct[k][j] = cterm[k * Dd + d + j] / omp;
      pw[k] = powf(p[k], (float)(c * LCH + 1));
    }
    float bo[4];
    #pragma unroll
    for (int j = 0; j < 4; ++j) bo[j] = b_out[d + j];
    size_t ybase = ((size_t)(b*Tt + c*LCH)) * Ee + d;
    size_t gbase = ((size_t)(b*Tt + c*LCH)) * Dd + d;
    for (int i = 0; i < LCH; ++i){
      f32x4 accv = {bo[0], bo[1], bo[2], bo[3]};
      #pragma unroll
      for (int k = 0; k < 4; ++k){
        uint2 yv = *(const uint2*)&Y[ybase + (size_t)k * Dd];
        zv[k][0] = p[k]*zv[k][0] + lo16(yv.x);
        zv[k][1] = p[k]*zv[k][1] + hi16(yv.x);
        zv[k][2] = p[k]*zv[k][2] + lo16(yv.y);
        zv[k][3] = p[k]*zv[k][3] + hi16(yv.y);
        float omw = 1.0f - pw[k];
        accv[0] += zv[k][0] + ct[k][0]*omw;
        accv[1] += zv[k][1] + ct[k][1]*omw;
        accv[2] += zv[k][2] + ct[k][2]*omw;
        accv[3] += zv[k][3] + ct[k][3]*omw;
        pw[k] *= p[k];
      }
      *(f32x4*)&g[gbase] = accv;
      ybase += Ee; gbase += Dd;
    }
  } else {
    int gid  = (bid - 128) * 4 + (tid >> 6);
    int lane = tid & 63;
    int d = gid & 1023, k = (gid >> 10) & 3, b = gid >> 12;
    const float* wrow = W_in + (size_t)(k*Dd + d) * Dd;
    const float* vv   = vfull + ((size_t)(b*Kk + k) << 10);
    float s = 0.f;
    #pragma unroll
    for (int j = 0; j < 4; ++j){
      int base = lane*4 + j*256;
      float4 w4 = *(const float4*)(wrow + base);
      float4 v4 = *(const float4*)(vv + base);
      s += w4.x*v4.x + w4.y*v4.y + w4.z*v4.z + w4.w*v4.w;
    }
    for (int off = 32; off; off >>= 1) s += __shfl_down(s, off);
    if (lane == 0){
      float p  = sigm(dlog[k]);
      float pT = powf(p, (float)Tt);
      float omp = 1.0f - p;
      float geo = (omp < 1e-12f) ? (float)Tt : (1.0f - pT) / omp;
      slast[gid] = pT * s0[gid] + s + b_in[k*Dd + d] * geo;
    }
  }
}

// ---------------------------------------------------------------------------
extern "C" void kernel_launch(void* const* d_in, const int* in_sizes, int n_in,
                              void* d_out, int out_size, void* d_ws, size_t ws_size,
                              hipStream_t stream){
  const float* u     = (const float*)d_in[0];
  const float* s0    = (const float*)d_in[1];
  const float* W_in  = (const float*)d_in[2];
  const float* b_in  = (const float*)d_in[3];
  const float* W_out = (const float*)d_in[4];
  const float* b_out = (const float*)d_in[5];
  const float* dlog  = (const float*)d_in[6];

  float* g_out     = (float*)d_out;                      // B*T*D
  float* slast_out = g_out + (size_t)BT * Dd;            // B*K*D

  char* ws = (char*)d_ws;
  if (ws_size < 115490816ull) return;
  ushort* U_bf    = (ushort*)(ws);                       // 16 MB
  ushort* WinT    = (ushort*)(ws + 16777216);            //  8 MB
  ushort* Wout_bf = (ushort*)(ws + 25165824);            //  8 MB
  ushort* Mcat    = (ushort*)(ws + 33554432);            //  8 MB
  ushort* Y       = (ushort*)(ws + 41943040);            // 64 MB
  float*  carry   = (float*)(ws + 109051904);            //  2 MB
  float*  incoming= (float*)(ws + 111149056);            //  2 MB
  float*  z0buf   = (float*)(ws + 113246208);            // 64 KB
  float*  cterm   = (float*)(ws + 113311744);            // 16 KB
  float*  vpart   = (float*)(ws + 113328128);            //  2 MB
  float*  vfull   = (float*)(ws + 115425280);            // 64 KB

  // 1) fused prep
  k_prep_all<<<5376, 256, 0, stream>>>(u, dlog, vpart, U_bf,
                                       W_in, WinT,
                                       W_out, s0, b_in, Wout_bf, z0buf, cterm);

  // 2) Mcat[(k,d), d'] = sum_j Wout[d, kD+j] * WinT[d', kD+j]
  gemm_nt<<<dim3(8, 8, 4), 256, 0, stream>>>(Wout_bf, WinT, Mcat,
                                             1024, Ee, Ee, Dd,
                                             1024L, 1024L, 1048576L);
  // 3) Y = U @ Mcat^T + fused chunk carries (2 blocks/CU, no spill)
  gemm_big<<<1024, 256, 0, stream>>>(U_bf, Mcat, Y, dlog, carry);

  // 4) fused mid: scanInc [0,64) | vcomb [64,128)
  k_mid<<<128, 256, 0, stream>>>(carry, z0buf, dlog, incoming, vpart, vfull);

  // 5) fused final: scanB [0,128) | slast [128,4224)
  k_final<<<4224, 256, 0, stream>>>(Y, incoming, dlog, b_out, cterm, g_out,
                                    W_in, vfull, s0, b_in, slast_out);
}

// Round 19
// 153.125 us; speedup vs baseline: 2.1095x; 1.0120x over previous
//
#include <hip/hip_runtime.h>

// ---------------------------------------------------------------------------
// StateBank R19 = R15 (best: 153.3us; gemm 83.8us @35% MfmaUtil) verbatim
// + T5 s_setprio(1/0) around the MFMA cluster. With 2 blocks/CU the waves
// of the two blocks are at different phases (one MFMA, one staging) -> the
// CU scheduler has something to arbitrate (m190's null was single-block
// lockstep; prerequisite holds here). Single change, clean A/B.
// ---------------------------------------------------------------------------

#define Bb 4
#define Tt 2048
#define Dd 1024
#define Kk 4
#define BT (Bb*Tt)          // 8192
#define Ee (Kk*Dd)          // 4096
#define NCH 32              // scan chunks
#define LCH 64              // chunk length (NCH*LCH = T)

typedef __bf16 bf16x8 __attribute__((ext_vector_type(8)));
typedef float  f32x4  __attribute__((ext_vector_type(4)));

__device__ __forceinline__ float bf2f(ushort u){
  union { unsigned int i; float f; } x; x.i = ((unsigned int)u) << 16; return x.f;
}
__device__ __forceinline__ ushort f2bf(float f){
  union { unsigned int i; float f; } x; x.f = f;
  unsigned int i = x.i;
  return (ushort)((i + 0x7FFFu + ((i >> 16) & 1u)) >> 16);   // RNE
}
__device__ __forceinline__ float lo16(unsigned u){
  union { unsigned i; float f; } x; x.i = u << 16; return x.f;
}
__device__ __forceinline__ float hi16(unsigned u){
  union { unsigned i; float f; } x; x.i = u & 0xFFFF0000u; return x.f;
}
__device__ __forceinline__ float sigm(float x){ return 1.0f / (1.0f + expf(-x)); }

// ---------------- fused prep: u-pass | W_in transpose | W_out pass ----------
__global__ __launch_bounds__(256) void k_prep_all(
    const float* __restrict__ u, const float* __restrict__ dlog,
    float* __restrict__ vpart, ushort* __restrict__ U_bf,
    const float* __restrict__ W_in, ushort* __restrict__ WinT,
    const float* __restrict__ Wout, const float* __restrict__ s0,
    const float* __restrict__ b_in, ushort* __restrict__ Wout_bf,
    float* __restrict__ z0, float* __restrict__ cterm){
  const int bid = blockIdx.x;
  const int tid = threadIdx.x;

  if (bid < 128){
    int x = bid, c = x & 31, b = x >> 5;
    int d0 = tid * 4;
    float p[4];
    #pragma unroll
    for (int k = 0; k < 4; ++k) p[k] = sigm(dlog[k]);
    f32x4 a0 = {0,0,0,0}, a1 = {0,0,0,0}, a2 = {0,0,0,0}, a3 = {0,0,0,0};
    size_t ub = ((size_t)(b*Tt + c*LCH)) * Dd + d0;
    for (int i = 0; i < LCH; ++i){
      f32x4 uv = *(const f32x4*)(u + ub);
      ushort4 ob; ob.x = f2bf(uv[0]); ob.y = f2bf(uv[1]);
      ob.z = f2bf(uv[2]); ob.w = f2bf(uv[3]);
      *(ushort4*)(U_bf + ub) = ob;
      a0 = p[0]*a0 + uv; a1 = p[1]*a1 + uv; a2 = p[2]*a2 + uv; a3 = p[3]*a3 + uv;
      ub += Dd;
    }
    size_t vb = ((size_t)x * Kk) * Dd + d0;
    *(f32x4*)(vpart + vb)          = a0;
    *(f32x4*)(vpart + vb + Dd)     = a1;
    *(f32x4*)(vpart + vb + 2*Dd)   = a2;
    *(f32x4*)(vpart + vb + 3*Dd)   = a3;
  } else if (bid < 4224){
    __shared__ float tile[32][33];
    int bb = bid - 128;
    int c0 = (bb & 31) * 32, r0 = (bb >> 5) * 32;
    int tx = tid & 31, ty = tid >> 5;     // 32 x 8
    #pragma unroll
    for (int j = 0; j < 4; ++j)
      tile[ty + j*8][tx] = W_in[(size_t)(r0 + ty + j*8) * Dd + c0 + tx];
    __syncthreads();
    #pragma unroll
    for (int j = 0; j < 4; ++j)
      WinT[(size_t)(c0 + ty + j*8) * Ee + r0 + tx] = f2bf(tile[tx][ty + j*8]);
  } else {
    int gid  = (bid - 4224) * 4 + (tid >> 6);   // k*1024 + d
    int lane = tid & 63;
    int d = gid & 1023, k = gid >> 10;
    const float* wrow = Wout + (size_t)d * Ee + k * Dd;
    ushort*      wbf  = Wout_bf + (size_t)d * Ee + k * Dd;
    const float* bv   = b_in + k * Dd;
    float sc = 0.f, sz0 = 0.f, sz1 = 0.f, sz2 = 0.f, sz3 = 0.f;
    #pragma unroll
    for (int j = 0; j < 4; ++j){
      int base = lane*4 + j*256;
      float4 wv = *(const float4*)(wrow + base);
      ushort4 ob; ob.x = f2bf(wv.x); ob.y = f2bf(wv.y); ob.z = f2bf(wv.z); ob.w = f2bf(wv.w);
      *(ushort4*)(wbf + base) = ob;
      float4 bb4 = *(const float4*)(bv + base);
      sc += wv.x*bb4.x + wv.y*bb4.y + wv.z*bb4.z + wv.w*bb4.w;
      #pragma unroll
      for (int b = 0; b < 4; ++b){
        const float* sv = s0 + ((size_t)(b*Kk + k) << 10) + base;
        float4 s4 = *(const float4*)sv;
        float acc = wv.x*s4.x + wv.y*s4.y + wv.z*s4.z + wv.w*s4.w;
        if (b == 0) sz0 += acc; else if (b == 1) sz1 += acc;
        else if (b == 2) sz2 += acc; else sz3 += acc;
      }
    }
    for (int off = 32; off; off >>= 1){
      sc  += __shfl_down(sc, off);
      sz0 += __shfl_down(sz0, off);
      sz1 += __shfl_down(sz1, off);
      sz2 += __shfl_down(sz2, off);
      sz3 += __shfl_down(sz3, off);
    }
    if (lane == 0){
      cterm[gid] = sc;
      z0[gid]          = sz0;
      z0[gid + 4096]   = sz1;
      z0[gid + 8192]   = sz2;
      z0[gid + 12288]  = sz3;
    }
  }
}

// ---------------- small NT GEMM (m97 structure) for Mcat --------------------
__global__ __launch_bounds__(256) void gemm_nt(const ushort* __restrict__ A,
                                               const ushort* __restrict__ B,
                                               ushort* __restrict__ C,
                                               int Kred, int lda, int ldb, int ldc,
                                               long aBatch, long bBatch, long cBatch){
  __shared__ ushort As[128 * 32];
  __shared__ ushort Bs[128 * 32];
  A += (long)blockIdx.z * aBatch;
  B += (long)blockIdx.z * bBatch;
  C += (long)blockIdx.z * cBatch;
  const int tid  = threadIdx.x;
  const int lane = tid & 63;
  const int w    = tid >> 6;
  const int wr   = w >> 1, wc = w & 1;
  const int rowBase = blockIdx.x * 128;
  const int colBase = blockIdx.y * 128;

  f32x4 acc[4][4] = {};
  const int krow = (lane >> 4) * 8;
  const int rsel = lane & 15;

  for (int kk = 0; kk < Kred; kk += 32){
    __syncthreads();
    #pragma unroll
    for (int i = 0; i < 2; ++i){
      int c  = i * 256 + tid;
      int r  = c >> 2;
      int c8 = (c & 3) * 8;
      const ushort* ga = A + (size_t)(rowBase + r) * lda + kk + c8;
      const ushort* gb = B + (size_t)(colBase + r) * ldb + kk + c8;
      __builtin_amdgcn_global_load_lds((const __attribute__((address_space(1))) void*)ga,
                                       (__attribute__((address_space(3))) void*)&As[c * 8],
                                       16, 0, 0);
      __builtin_amdgcn_global_load_lds((const __attribute__((address_space(1))) void*)gb,
                                       (__attribute__((address_space(3))) void*)&Bs[c * 8],
                                       16, 0, 0);
    }
    asm volatile("s_waitcnt vmcnt(0)" ::: "memory");
    __syncthreads();

    bf16x8 Af[4], Bf[4];
    #pragma unroll
    for (int mi = 0; mi < 4; ++mi)
      Af[mi] = *(const bf16x8*)&As[(wr*64 + mi*16 + rsel) * 32 + krow];
    #pragma unroll
    for (int ni = 0; ni < 4; ++ni)
      Bf[ni] = *(const bf16x8*)&Bs[(wc*64 + ni*16 + rsel) * 32 + krow];
    #pragma unroll
    for (int mi = 0; mi < 4; ++mi)
      #pragma unroll
      for (int ni = 0; ni < 4; ++ni)
        acc[mi][ni] = __builtin_amdgcn_mfma_f32_16x16x32_bf16(Af[mi], Bf[ni], acc[mi][ni], 0, 0, 0);
  }

  #pragma unroll
  for (int mi = 0; mi < 4; ++mi){
    #pragma unroll
    for (int ni = 0; ni < 4; ++ni){
      int r0 = rowBase + wr*64 + mi*16 + (lane >> 4) * 4;
      int c0 = colBase + wc*64 + ni*16 + (lane & 15);
      #pragma unroll
      for (int q = 0; q < 4; ++q)
        C[(size_t)(r0 + q) * ldc + c0] = f2bf(acc[mi][ni][q]);
    }
  }
}

// ---------------- gemm_big: Y = U_bf @ Mcat^T, 128x256 block, 4 waves -------
// LDS: buf c @ c*12288 ushorts {A [128][32] @0, B [256][32] @4096}. 48KB dbuf.
#define STAGE_A(GB, LOFF)                                                      \
  { _Pragma("unroll")                                                          \
    for (int i_ = 0; i_ < 2; ++i_){                                            \
      int c_ = tid + i_*256;                                                   \
      int row_ = c_ >> 2;                                                      \
      int ss_ = (c_ & 3) ^ ((row_ >> 1) & 3);                                  \
      const ushort* g_ = (GB) + (size_t)row_ * 1024 + ss_ * 8;                 \
      __builtin_amdgcn_global_load_lds(                                        \
        (const __attribute__((address_space(1))) void*)g_,                     \
        (__attribute__((address_space(3))) void*)&lds[(LOFF) + c_*8],          \
        16, 0, 0);                                                             \
    } }

#define STAGE_B(GB, LOFF)                                                      \
  { _Pragma("unroll")                                                          \
    for (int i_ = 0; i_ < 4; ++i_){                                            \
      int c_ = tid + i_*256;                                                   \
      int row_ = c_ >> 2;                                                      \
      int ss_ = (c_ & 3) ^ ((row_ >> 1) & 3);                                  \
      const ushort* g_ = (GB) + (size_t)row_ * 1024 + ss_ * 8;                 \
      __builtin_amdgcn_global_load_lds(                                        \
        (const __attribute__((address_space(1))) void*)g_,                     \
        (__attribute__((address_space(3))) void*)&lds[(LOFF) + 4096 + c_*8],   \
        16, 0, 0);                                                             \
    } }

#define LOAD_A4(DST)                                                           \
  { _Pragma("unroll")                                                          \
    for (int mi_ = 0; mi_ < 4; ++mi_){                                         \
      int r_ = wm*64 + mi_*16 + rsel;                                          \
      int uo_ = r_*32 + kq*8;                                                  \
      uo_ ^= ((uo_ >> 6) & 3) << 3;                                            \
      DST[mi_] = *(const bf16x8*)&lds[cbase + uo_];                            \
    } }

#define LOAD_B8(DST)                                                           \
  { _Pragma("unroll")                                                          \
    for (int ni_ = 0; ni_ < 8; ++ni_){                                         \
      int r_ = wn*128 + ni_*16 + rsel;                                         \
      int uo_ = r_*32 + kq*8;                                                  \
      uo_ ^= ((uo_ >> 6) & 3) << 3;                                            \
      DST[ni_] = *(const bf16x8*)&lds[cbase + 4096 + uo_];                     \
    } }

#define XB(R) ((((R) & 3) ^ (((R) >> 2) & 3)) << 5)
#define BAR() __builtin_amdgcn_s_barrier()

__global__ __launch_bounds__(256, 2) void gemm_big(const ushort* __restrict__ A,
                                                   const ushort* __restrict__ B,
                                                   ushort* __restrict__ C,
                                                   const float* __restrict__ dlog,
                                                   float* __restrict__ carry){
  __shared__ ushort lds[24576];       // 48 KB dbuf -> 2 blocks/CU
  const int tid  = threadIdx.x;
  const int lane = tid & 63;
  const int w    = tid >> 6;          // 0..3
  const int wm   = w >> 1;            // 2 M-waves
  const int wn   = w & 1;             // 2 N-waves (128-col strips)
  const int rsel = lane & 15;
  const int kq   = lane >> 4;

  // grid 1024 = 64M x 16N tiles; XCD region 8M x 16N.
  int bid = blockIdx.x;
  int xcd = bid & 7, rr = bid >> 3;   // rr 0..127
  const int rowBase = (xcd * 8 + (rr & 7)) * 128;   // 64 M-tiles (bt)
  const int colBase = (rr >> 3) * 256;              // 16 N-tiles (Y cols)

  const ushort* Ag = A + (size_t)rowBase * 1024;
  const ushort* Bg = B + (size_t)colBase * 1024;

  f32x4 acc[4][8] = {};

  // prologue: tile0 -> buf0, tile1 -> buf1 (6 loads/thread each)
  STAGE_A(Ag +  0, 0);
  STAGE_B(Bg +  0, 0);
  STAGE_A(Ag + 32, 12288);
  STAGE_B(Bg + 32, 12288);
  asm volatile("s_waitcnt vmcnt(6)" ::: "memory");   // tile0 landed
  BAR();

  for (int t = 0; t < 32; ++t){
    const int cbase = (t & 1) * 12288;
    bf16x8 af[4], bf[8];
    LOAD_A4(af); LOAD_B8(bf);
    __builtin_amdgcn_s_setprio(1);
    #pragma unroll
    for (int mi = 0; mi < 4; ++mi)
      #pragma unroll
      for (int ni = 0; ni < 8; ++ni)
        acc[mi][ni] = __builtin_amdgcn_mfma_f32_16x16x32_bf16(af[mi], bf[ni], acc[mi][ni], 0, 0, 0);
    __builtin_amdgcn_s_setprio(0);
    asm volatile("s_waitcnt lgkmcnt(0)" ::: "memory");
    BAR();
    if (t < 30){
      STAGE_A(Ag + (t+2)*32, cbase);
      STAGE_B(Bg + (t+2)*32, cbase);
      asm volatile("s_waitcnt vmcnt(6)" ::: "memory");   // tile t+1 landed
    } else {
      asm volatile("s_waitcnt vmcnt(0)" ::: "memory");
    }
    BAR();
  }

  // ---- epilogue: two 128-col halves; each = R12's proven machinery.
  #pragma unroll
  for (int h = 0; h < 2; ++h){
    if (wn == h){
      #pragma unroll
      for (int mi = 0; mi < 4; ++mi){
        #pragma unroll
        for (int ni = 0; ni < 8; ++ni){
          #pragma unroll
          for (int q = 0; q < 4; ++q){
            int row = wm*64 + mi*16 + (lane >> 4)*4 + q;
            int col = ni*16 + rsel;
            int byte = (row*256 + col*2) ^ XB(row);
            *(ushort*)((char*)lds + byte) = f2bf(acc[mi][ni][q]);
          }
        }
      }
    }
    __syncthreads();

    const int colH = colBase + h*128;
    // fused scanA carries: 2 chunks x 64 col-pairs -> threads 0..127
    if (tid < 128){
      const int k_blk = colH >> 10;
      const int b_blk = rowBase >> 11;
      const int ch0   = (rowBase & 2047) >> 6;
      const int d0    = colH & 1023;
      const float p   = sigm(dlog[k_blk]);
      int cp = tid & 63, ch = tid >> 6;
      float a0 = 0.f, a1 = 0.f;
      for (int i = 0; i < 64; ++i){
        int row = ch*64 + i;
        int byte = (row*256 + cp*4) ^ XB(row);
        unsigned v = *(const unsigned*)((char*)lds + byte);
        a0 = p * a0 + lo16(v);
        a1 = p * a1 + hi16(v);
      }
      float* cdst = &carry[(size_t)((b_blk*Kk + k_blk)*NCH + ch0 + ch) * Dd + d0 + cp*2];
      cdst[0] = a0; cdst[1] = a1;
    }

    // coalesced Y write: 16B per lane, 8 sweeps
    #pragma unroll
    for (int j = 0; j < 8; ++j){
      int idx = tid + j*256;
      int r = idx >> 4, c16 = idx & 15;
      int byte = (r*256 + c16*16) ^ XB(r);
      f32x4 v = *(const f32x4*)((char*)lds + byte);
      *(f32x4*)&C[(size_t)(rowBase + r) * Ee + colH + c16*8] = v;
    }
    __syncthreads();
  }
}

// ---------------- fused mid: scanInc | vcomb --------------------------------
__global__ __launch_bounds__(256) void k_mid(const float* __restrict__ carry,
                                             const float* __restrict__ z0,
                                             const float* __restrict__ dlog,
                                             float* __restrict__ incoming,
                                             const float* __restrict__ vpart,
                                             float* __restrict__ vfull){
  int bid = blockIdx.x, tid = threadIdx.x;
  if (bid < 64){
    int idx = bid * 256 + tid;
    int k = (idx >> 10) & 3;
    int bk = idx >> 10, d = idx & 1023;
    float p  = sigm(dlog[k]);
    float dL = powf(p, (float)LCH);
    float inc = z0[idx];
    for (int c = 0; c < NCH; ++c){
      size_t o = ((size_t)(bk * NCH + c)) * Dd + d;
      incoming[o] = inc;
      inc = dL * inc + carry[o];
    }
  } else {
    int idx = (bid - 64) * 256 + tid;
    int k = (idx >> 10) & 3, b = idx >> 12, d = idx & 1023;
    float p  = sigm(dlog[k]);
    float dL = powf(p, (float)LCH);
    float v = 0.f;
    for (int c = 0; c < NCH; ++c)
      v = dL * v + vpart[(((size_t)(b*NCH + c)) * Kk + k) * Dd + d];
    vfull[idx] = v;
  }
}

// ---------------- fused final: scanB (2 d/thread) | slast -------------------
__global__ __launch_bounds__(256) void k_final(const ushort* __restrict__ Y,
                                               const float* __restrict__ incoming,
                                               const float* __restrict__ dlog,
                                               const float* __restrict__ b_out,
                                               const float* __restrict__ cterm,
                                               float* __restrict__ g,
                                               const float* __restrict__ W_in,
                                               const float* __restrict__ vfull,
                                               const float* __restrict__ s0,
                                               const float* __restrict__ b_in,
                                               float* __restrict__ slast){
  int bid = blockIdx.x, tid = threadIdx.x;
  if (bid < 256){
    int x = bid >> 1;
    int c = x & 31, b = x >> 5;
    int d = (bid & 1) * 512 + tid * 2;
    float p[4], ct0[4], ct1[4], pw[4];
    float z0v[4], z1v[4];
    #pragma unroll
    for (int k = 0; k < 4; ++k){
      p[k]  = sigm(dlog[k]);
      size_t io = ((size_t)(((b*Kk + k))*NCH + c)) * Dd + d;
      z0v[k] = incoming[io];
      z1v[k] = incoming[io + 1];
      float omp = fmaxf(1.0f - p[k], 1e-30f);
      ct0[k] = cterm[k * Dd + d] / omp;
      ct1[k] = cterm[k * Dd + d + 1] / omp;
      pw[k] = powf(p[k], (float)(c * LCH + 1));
    }
    float bo0 = b_out[d], bo1 = b_out[d + 1];
    size_t ybase = ((size_t)(b*Tt + c*LCH)) * Ee + d;
    size_t gbase = ((size_t)(b*Tt + c*LCH)) * Dd + d;
    for (int i = 0; i < LCH; ++i){
      float acc0 = bo0, acc1 = bo1;
      #pragma unroll
      for (int k = 0; k < 4; ++k){
        unsigned yv = *(const unsigned*)&Y[ybase + (size_t)k * Dd];
        z0v[k] = p[k] * z0v[k] + lo16(yv);
        z1v[k] = p[k] * z1v[k] + hi16(yv);
        float omw = 1.0f - pw[k];
        acc0 += z0v[k] + ct0[k] * omw;
        acc1 += z1v[k] + ct1[k] * omw;
        pw[k] *= p[k];
      }
      *(float2*)&g[gbase] = make_float2(acc0, acc1);
      ybase += Ee; gbase += Dd;
    }
  } else {
    int gid  = (bid - 256) * 4 + (tid >> 6);
    int lane = tid & 63;
    int d = gid & 1023, k = (gid >> 10) & 3, b = gid >> 12;
    const float* wrow = W_in + (size_t)(k*Dd + d) * Dd;
    const float* vv   = vfull + ((size_t)(b*Kk + k) << 10);
    float s = 0.f;
    #pragma unroll
    for (int j = 0; j < 4; ++j){
      int base = lane*4 + j*256;
      float4 w4 = *(const float4*)(wrow + base);
      float4 v4 = *(const float4*)(vv + base);
      s += w4.x*v4.x + w4.y*v4.y + w4.z*v4.z + w4.w*v4.w;
    }
    for (int off = 32; off; off >>= 1) s += __shfl_down(s, off);
    if (lane == 0){
      float p  = sigm(dlog[k]);
      float pT = powf(p, (float)Tt);
      float omp = 1.0f - p;
      float geo = (omp < 1e-12f) ? (float)Tt : (1.0f - pT) / omp;
      slast[gid] = pT * s0[gid] + s + b_in[k*Dd + d] * geo;
    }
  }
}

// ---------------------------------------------------------------------------
extern "C" void kernel_launch(void* const* d_in, const int* in_sizes, int n_in,
                              void* d_out, int out_size, void* d_ws, size_t ws_size,
                              hipStream_t stream){
  const float* u     = (const float*)d_in[0];
  const float* s0    = (const float*)d_in[1];
  const float* W_in  = (const float*)d_in[2];
  const float* b_in  = (const float*)d_in[3];
  const float* W_out = (const float*)d_in[4];
  const float* b_out = (const float*)d_in[5];
  const float* dlog  = (const float*)d_in[6];

  float* g_out     = (float*)d_out;                      // B*T*D
  float* slast_out = g_out + (size_t)BT * Dd;            // B*K*D

  char* ws = (char*)d_ws;
  if (ws_size < 115490816ull) return;
  ushort* U_bf    = (ushort*)(ws);                       // 16 MB
  ushort* WinT    = (ushort*)(ws + 16777216);            //  8 MB
  ushort* Wout_bf = (ushort*)(ws + 25165824);            //  8 MB
  ushort* Mcat    = (ushort*)(ws + 33554432);            //  8 MB
  ushort* Y       = (ushort*)(ws + 41943040);            // 64 MB
  float*  carry   = (float*)(ws + 109051904);            //  2 MB
  float*  incoming= (float*)(ws + 111149056);            //  2 MB
  float*  z0buf   = (float*)(ws + 113246208);            // 64 KB
  float*  cterm   = (float*)(ws + 113311744);            // 16 KB
  float*  vpart   = (float*)(ws + 113328128);            //  2 MB
  float*  vfull   = (float*)(ws + 115425280);            // 64 KB

  // 1) fused prep
  k_prep_all<<<5248, 256, 0, stream>>>(u, dlog, vpart, U_bf,
                                       W_in, WinT,
                                       W_out, s0, b_in, Wout_bf, z0buf, cterm);

  // 2) Mcat[(k,d), d'] = sum_j Wout[d, kD+j] * WinT[d', kD+j]
  gemm_nt<<<dim3(8, 8, 4), 256, 0, stream>>>(Wout_bf, WinT, Mcat,
                                             1024, Ee, Ee, Dd,
                                             1024L, 1024L, 1048576L);
  // 3) Y = U @ Mcat^T + fused chunk carries (2 blk/CU, setprio on MFMA)
  gemm_big<<<1024, 256, 0, stream>>>(U_bf, Mcat, Y, dlog, carry);

  // 4) fused mid: scanInc [0,64) | vcomb [64,128)
  k_mid<<<128, 256, 0, stream>>>(carry, z0buf, dlog, incoming, vpart, vfull);

  // 5) fused final: scanB [0,256) | slast [256,4352)
  k_final<<<4352, 256, 0, stream>>>(Y, incoming, dlog, b_out, cterm, g_out,
                                    W_in, vfull, s0, b_in, slast_out);
}